// Round 4
// baseline (69.969 us; speedup 1.0000x reference)
//
#include <hip/hip_runtime.h>

// ArithmeticCompute: circle-encoded modular arithmetic over PRIMES.
// out[3][B*S][10][2] = {add, sub, mul} on the unit circle.
//
// R14: occupancy experiment. R13's null (packing halved hot-loop issue count
// AND code bytes -> dur_us -1%) refuted issue-bound and I-fetch-bound
// theories. The one invariant across R10-R13: 2 threads/pair -> 2048 waves
// = 8 waves/CU = 2 waves/SIMD. If the kernel is dependent-chain
// latency-bound, no arithmetic restructure at fixed occupancy can show it.
//
// R14 = R13's packed bodies at 4 THREADS PER PAIR:
//   262144 threads, 1024 blocks x 256, 4 blocks/CU = 16 waves/CU =
//   4 waves/SIMD (2x latency hiding), ~2x less work on critical thread.
//   Subsets (wave-uniform, t>>6): {29,2} / {23,13} / {19,17} / {11,7,5,3}
//   pair-loop pk costs 197/157/145/39; imbalance tolerated since 4
//   blocks/CU mix waves on each SIMD. Slot offsets partitioned
//   {9,0}/{8,5}/{7,6}/{4,3,2,1} -> write-back-into-ta stays race-free.
//   64 pairs/block -> phase 1/3 I/O = exactly 320 float4 (no float2 tail).
//   __launch_bounds__(256,4): VGPR cap 128; p29 body ~90 live. LDS 11.3KB.
//
// mul per (pair, prime): quartet-folded softmax outer product, packed v2
// (one v_pk_fma_f32 per (I,J); sign folded into (ua,va)/(ua,-va) pick).

#define TEMP_LOG2E 1442.6950408889634f  // softmax_temperature * log2(e)

typedef float v2 __attribute__((ext_vector_type(2)));

constexpr double PI_D = 3.14159265358979323846264338327950288;

constexpr double tay_cos(double x) {
    double x2 = x * x, term = 1.0, sum = 1.0;
    for (int k = 1; k <= 15; ++k) { term *= -x2 / double((2 * k - 1) * (2 * k)); sum += term; }
    return sum;
}
constexpr double tay_sin(double x) {
    double x2 = x * x, term = x, sum = x;
    for (int k = 1; k <= 15; ++k) { term *= -x2 / double((2 * k) * (2 * k + 1)); sum += term; }
    return sum;
}
constexpr double ang_red(int r, int P) {  // 2*pi*r/P reduced to [-pi, pi]
    double x = 2.0 * PI_D * double(r) / double(P);
    return (x > PI_D) ? x - 2.0 * PI_D : x;
}

// ---- compile-time integer sequences ----
template <int... Is> struct iseq {};
template <int N, int... Is> struct mkseq : mkseq<N - 1, N - 1, Is...> {};
template <int... Is> struct mkseq<0, Is...> { using type = iseq<Is...>; };
template <int N> using iseq_t = typename mkseq<N>::type;

// ---- per-(P,R) compile-time table scalars: guaranteed literals ----
template <int P, int R> struct CS {
    static constexpr float tc = (float)(double(TEMP_LOG2E) * tay_cos(ang_red(R, P)));
    static constexpr float ts = (float)(double(TEMP_LOG2E) * tay_sin(ang_red(R, P)));
    static constexpr float ec = (float)tay_cos(ang_red(R, P));
    static constexpr float es = (float)tay_sin(ang_red(R, P));
};

// Packed similarity for the residue pair (J, P-J):
//   sim_J   = c*tc + s*ts   (lane .x)
//   sim_P-J = c*tc - s*ts   (lane .y)
template <int P, int J>
__device__ __forceinline__ v2 sim2(v2 c2, v2 s2, v2 nm2) {
    const v2 tc2 = {CS<P, J>::tc, CS<P, J>::tc};
    const v2 ts2 = {CS<P, J>::ts, -CS<P, J>::ts};
    return s2 * ts2 + (c2 * tc2 + nm2);   // 2x pk_fma
}

// ---- pass 1: max of scaled similarities (packed pair chains) ----
template <int P, int J>
__device__ __forceinline__ void smax_step(v2 c2, v2 s2, v2& m2) {
    const v2 tc2 = {CS<P, J>::tc, CS<P, J>::tc};
    const v2 ts2 = {CS<P, J>::ts, -CS<P, J>::ts};
    m2 = __builtin_elementwise_max(m2, s2 * ts2 + c2 * tc2);
}
template <int P, int... J>
__device__ __forceinline__ float smax_impl(float c, float s, iseq<J...>) {
    const v2 c2 = {c, c}, s2 = {s, s};
    v2 m2 = {c * CS<P, 0>::tc, -3.0e38f};   // residue 0 (ts = 0)
    (smax_step<P, J + 1>(c2, s2, m2), ...);
    return fmaxf(m2.x, m2.y);
}
template <int P>
__device__ __forceinline__ float simmax(float c, float s) {
    return smax_impl<P>(c, s, iseq_t<(P - 1) / 2>{});
}

// ---- pass 2: b-side folded softmax numerators, packed (ub,vb) ----
template <int P, int J, int H>
__device__ __forceinline__ void b_step(v2 cb2, v2 sb2, v2 nmb2, float& Sb,
                                       v2 (&uvb)[H]) {
    const v2 u2 = sim2<P, J>(cb2, sb2, nmb2);
    const float e1 = __builtin_amdgcn_exp2f(u2.x);
    const float e2 = __builtin_amdgcn_exp2f(u2.y);
    uvb[J - 1] = (v2){e1 + e2, e1 - e2};
    Sb += e1 + e2;
}
template <int P, int H, int... J>
__device__ __forceinline__ void b_fold(v2 cb2, v2 sb2, v2 nmb2, float& Sb,
                                       v2 (&uvb)[H], iseq<J...>) {
    (b_step<P, J + 1, H>(cb2, sb2, nmb2, Sb, uvb), ...);
}

// ---- pass 3: pair loop, one pk_fma per (I,J), indices template constants ----
template <int P, int I, int J, int H>
__device__ __forceinline__ void pair_step(v2 uva_p, v2 uva_m,
                                          const v2 (&uvb)[H], v2 (&acc)[H]) {
    constexpr int K0 = (I * J) % P;     // never 0: P prime, 0 < I,J < P
    constexpr int KR = (K0 <= H) ? K0 : P - K0;
    if constexpr (K0 <= H) acc[KR - 1] = uva_p * uvb[J - 1] + acc[KR - 1];
    else                   acc[KR - 1] = uva_m * uvb[J - 1] + acc[KR - 1];
}
template <int P, int I, int H, int... J>
__device__ __forceinline__ void pair_row(v2 uva_p, v2 uva_m,
                                         const v2 (&uvb)[H], v2 (&acc)[H],
                                         iseq<J...>) {
    (pair_step<P, I, J + 1, H>(uva_p, uva_m, uvb, acc), ...);
}
template <int P, int I, int H>
__device__ __forceinline__ void a_step(v2 ca2, v2 sa2, v2 nma2, float& Sa,
                                       const v2 (&uvb)[H], v2 (&acc)[H]) {
    const v2 u2 = sim2<P, I>(ca2, sa2, nma2);
    const float f1 = __builtin_amdgcn_exp2f(u2.x);
    const float f2 = __builtin_amdgcn_exp2f(u2.y);
    const float ua = f1 + f2, va = f1 - f2;
    Sa += ua;
    const v2 uva_p = {ua, va};
    const v2 uva_m = {ua, -va};
    pair_row<P, I, H>(uva_p, uva_m, uvb, acc, iseq_t<H>{});
}
template <int P, int H, int... I>
__device__ __forceinline__ void a_fold(v2 ca2, v2 sa2, v2 nma2, float& Sa,
                                       const v2 (&uvb)[H], v2 (&acc)[H],
                                       iseq<I...>) {
    (a_step<P, I + 1, H>(ca2, sa2, nma2, Sa, uvb, acc), ...);
}

// ---- epilogue: re-encode (cos even in k, sin odd) ----
template <int P, int K, int H>
__device__ __forceinline__ void enc_step(const v2 (&acc)[H], float& accC, float& accS) {
    accC = fmaf(acc[K - 1].x, CS<P, K>::ec, accC);
    accS = fmaf(acc[K - 1].y, CS<P, K>::es, accS);
}
template <int P, int H, int... K>
__device__ __forceinline__ void enc_fold(const v2 (&acc)[H], float& accC, float& accS,
                                         iseq<K...>) {
    (enc_step<P, K + 1, H>(acc, accC, accS), ...);
}

template <int P>
__device__ __forceinline__ void mul_prime(float ca, float sa, float cb, float sb,
                                          float& oc, float& os) {
    static_assert(P % 2 == 1, "generic path requires odd P");
    constexpr int H = (P - 1) / 2;

    const float nma = -simmax<P>(ca, sa);
    const float nmb = -simmax<P>(cb, sb);

    const v2 ca2 = {ca, ca}, sa2 = {sa, sa}, nma2 = {nma, nma};
    const v2 cb2 = {cb, cb}, sb2 = {sb, sb}, nmb2 = {nmb, nmb};

    // b-side numerators (packed (ub, vb) per residue pair)
    const float eb0 = __builtin_amdgcn_exp2f(fmaf(cb, CS<P, 0>::tc, nmb));
    v2 uvb[H];
    float Sb = eb0;
    b_fold<P, H>(cb2, sb2, nmb2, Sb, uvb, iseq_t<H>{});

    // a-side outer loop + packed pair loop
    v2 acc[H] = {};
    const float ea0 = __builtin_amdgcn_exp2f(fmaf(ca, CS<P, 0>::tc, nma));
    float Sa = ea0;
    a_fold<P, H>(ca2, sa2, nma2, Sa, uvb, acc, iseq_t<H>{});

    // Zero row/column: contributes only to W[0].
    const float W0 = ea0 * Sb + eb0 * (Sa - ea0);

    float accC = W0, accS = 0.f;
    enc_fold<P, H>(acc, accC, accS, iseq_t<H>{});

    const float inv = __builtin_amdgcn_rcpf(Sa * Sb);
    oc = accC * inv;
    os = accS * inv;
}

// P = 2: closed form (templates (1,0), (-1,0); sin terms vanish).
template <>
__device__ __forceinline__ void mul_prime<2>(float ca, float sa, float cb, float sb,
                                             float& oc, float& os) {
    const float ka = ca * TEMP_LOG2E, kb = cb * TEMP_LOG2E;
    const float ma = fabsf(ka), mb = fabsf(kb);
    const float ea0 = __builtin_amdgcn_exp2f(ka - ma);
    const float ea1 = __builtin_amdgcn_exp2f(-ka - ma);
    const float eb0 = __builtin_amdgcn_exp2f(kb - mb);
    const float eb1 = __builtin_amdgcn_exp2f(-kb - mb);
    const float Sa = ea0 + ea1, Sb = eb0 + eb1;
    const float W0 = ea0 * Sb + eb0 * Sa - ea0 * eb0;
    const float W1 = ea1 * eb1;
    const float inv = __builtin_amdgcn_rcpf(Sa * Sb);
    oc = (W0 - W1) * inv;
    os = 0.f;
}

__global__ __launch_bounds__(256, 4) void arith_kernel(const float* __restrict__ a,
                                                       const float* __restrict__ b,
                                                       float* __restrict__ out,
                                                       int n_pairs) {
    // 64 pairs x 11 float2 slots (10 primes + pad). 11.3 KB total.
    __shared__ float2 ta[64 * 11], tb[64 * 11];

    const int t = threadIdx.x;                 // 0..255
    const int gb4 = blockIdx.x * 320;          // block base in float4
    const int planef4 = n_pairs * 5;           // plane size in float4
    float4* o4 = (float4*)out;
    const float4* a4 = (const float4*)a;
    const float4* b4 = (const float4*)b;

    // Phase 1: coalesced load + stage + add/sub stores.
    // 64 pairs x 5 float4 = 320 float4; iter 0 full, iter 1 first 64 lanes.
#pragma unroll
    for (int it = 0; it < 2; ++it) {
        const int k = it * 256 + t;            // float4 index 0..511
        if (k < 320) {
            const int pr = k / 5, j = k - pr * 5;  // pair, float4-within-pair
            const int sl = pr * 11 + 2 * j;
            const float4 av = a4[gb4 + k];
            const float4 bv = b4[gb4 + k];
            ta[sl]     = make_float2(av.x, av.y);
            ta[sl + 1] = make_float2(av.z, av.w);
            tb[sl]     = make_float2(bv.x, bv.y);
            tb[sl + 1] = make_float2(bv.z, bv.w);
            float4 addv, subv;
            addv.x = av.x * bv.x - av.y * bv.y;  addv.y = av.y * bv.x + av.x * bv.y;
            addv.z = av.z * bv.z - av.w * bv.w;  addv.w = av.w * bv.z + av.z * bv.w;
            subv.x = av.x * bv.x + av.y * bv.y;  subv.y = av.y * bv.x - av.x * bv.y;
            subv.z = av.z * bv.z + av.w * bv.w;  subv.w = av.w * bv.z - av.z * bv.w;
            o4[gb4 + k]           = addv;          // add plane
            o4[planef4 + gb4 + k] = subv;          // sub plane
        }
    }
    __syncthreads();

    // Phase 2: 4 threads per pair. Subset = t>>6 (wave-uniform):
    //   0:{29,2}  1:{23,13}  2:{19,17}  3:{11,7,5,3}
    // Results written back into the ta slot (subsets partition offsets
    // {9,0}/{8,5}/{7,6}/{4,3,2,1}; each slot's only phase-2 reader is its
    // writer).
    {
        const int rb = (t & 63) * 11;
        const int ss = t >> 6;

#define DO_PRIME(P, OFI)                                                     \
        {                                                                    \
            const float2 av = ta[rb + (OFI)];                                \
            const float2 bv = tb[rb + (OFI)];                                \
            float oc, os;                                                    \
            mul_prime<P>(av.x, av.y, bv.x, bv.y, oc, os);                    \
            ta[rb + (OFI)] = make_float2(oc, os);                            \
        }

        if (ss == 0) {
            DO_PRIME(29, 9)
            DO_PRIME(2, 0)
        } else if (ss == 1) {
            DO_PRIME(23, 8)
            DO_PRIME(13, 5)
        } else if (ss == 2) {
            DO_PRIME(19, 7)
            DO_PRIME(17, 6)
        } else {
            DO_PRIME(11, 4)
            DO_PRIME(7, 3)
            DO_PRIME(5, 2)
            DO_PRIME(3, 1)
        }
#undef DO_PRIME
    }
    __syncthreads();

    // Phase 3: coalesced LDS -> global for the mul plane.
#pragma unroll
    for (int it = 0; it < 2; ++it) {
        const int k = it * 256 + t;
        if (k < 320) {
            const int pr = k / 5, j = k - pr * 5;
            const int sl = pr * 11 + 2 * j;
            const float2 r0 = ta[sl], r1 = ta[sl + 1];
            o4[2 * planef4 + gb4 + k] = make_float4(r0.x, r0.y, r1.x, r1.y);
        }
    }
}

extern "C" void kernel_launch(void* const* d_in, const int* in_sizes, int n_in,
                              void* d_out, int out_size, void* d_ws, size_t ws_size,
                              hipStream_t stream) {
    const float* a = (const float*)d_in[0];
    const float* b = (const float*)d_in[1];
    float* out = (float*)d_out;
    const int n_pairs = in_sizes[0] / 20;   // B*S = 65536 (multiple of 64)
    const int n_blocks = n_pairs / 64;      // 1024 blocks of 256 threads

    dim3 block(256);
    dim3 grid(n_blocks);
    arith_kernel<<<grid, block, 0, stream>>>(a, b, out, n_pairs);
}